// Round 3
// baseline (746.155 us; speedup 1.0000x reference)
//
#include <hip/hip_runtime.h>
#include <hip/hip_bf16.h>
#include <stdint.h>

#define DEVI static __device__ __forceinline__

// Problem constants
constexpr int NPTS = 4096;     // N
constexpr int BN   = 16384;    // B*N

// ---------------- ws layout (float offsets) ----------------
// ws[0] holds the runtime dtype flag (1 = inputs are fp32, 0 = bf16).
// K/V tables are LAST so the compact path can omit them when ws_size is small.
constexpr size_t OFF_FLAG = 0;                          // unsigned flag
constexpr size_t OFF_XYZS = 16;                         // float4[BN]  (x,y,z,sq)
constexpr size_t OFF_WPK  = OFF_XYZS + 65536;           // float[256*144] att-MLP pack
constexpr size_t OFF_WPOS = OFF_WPK + 256 * 144;        // float[64*80] pos-MLP pack
constexpr size_t OFF_B2   = OFF_WPOS + 64 * 80;         // float[64] b_att2
constexpr size_t OFF_BP2  = OFF_B2 + 64;                // float[64] b_pos2
constexpr size_t OFF_WQKV = OFF_BP2 + 64;               // float[192*64]
constexpr size_t OFF_IDX  = OFF_WQKV + 192 * 64;        // uint[BN*16]
constexpr size_t OFF_KT   = OFF_IDX + (size_t)BN * 16;  // float[BN*64] (fast path only)
constexpr size_t OFF_VT   = OFF_KT + (size_t)BN * 64;   // float[BN*64] (fast path only)
constexpr size_t FULL_FLOATS = OFF_VT + (size_t)BN * 64;   // ~9.92 MB
// compact footprint = OFF_KT floats ~ 1.53 MB

DEVI float b2f(__hip_bfloat16 h) { return __bfloat162float(h); }

DEVI float us2f(unsigned short u) {
    __hip_bfloat16 h;
    *(unsigned short*)&h = u;
    return __bfloat162float(h);
}

DEVI unsigned short f2us(float f) {
    __hip_bfloat16 h = __float2bfloat16(f);
    return *(unsigned short*)&h;
}

// dtype-dispatched input load (element index i of logical array p)
DEVI float ldin(const void* p, size_t i, int f32) {
    return f32 ? ((const float*)p)[i] : b2f(((const __hip_bfloat16*)p)[i]);
}

// 64-bit xor-shuffle via two 32-bit shuffles
DEVI unsigned long long shflx64(unsigned long long v, int m) {
    unsigned lo = __shfl_xor((unsigned)(v & 0xffffffffull), m, 64);
    unsigned hi = __shfl_xor((unsigned)(v >> 32), m, 64);
    return ((unsigned long long)hi << 32) | lo;
}

// ---------------- dtype detector ----------------
// bf16 N(0,1) data: exponent field of every uint16 is < 140 (|x| < 2^13).
// fp32 data read as uint16: low halves are ~uniform -> ~45% have exp >= 140.
__global__ void detect_kernel(const void* xyz, unsigned* flagp) {
    __shared__ int s;
    int t = threadIdx.x;
    if (t == 0) s = 0;
    __syncthreads();
    const unsigned short* u = (const unsigned short*)xyz;
    int cnt = 0;
    for (int i = t; i < 2048; i += 256) {
        unsigned e = (u[i] >> 7) & 0xFFu;
        cnt += (e >= 140u);
    }
    atomicAdd(&s, cnt);
    __syncthreads();
    if (t == 0) *flagp = (s > 16) ? 1u : 0u;
}

// ---------------- prep: xyzs(float4) + packed fp32 weights ----------------
__global__ void prep_kernel(const void* xyz, const void* w_qkv,
                            const void* w_pos1, const void* b_pos1,
                            const void* w_pos2, const void* b_pos2,
                            const void* w_att1, const void* b_att1,
                            const void* w_att2, const void* b_att2,
                            float* ws) {
    int f32 = (int)((const unsigned*)ws)[OFF_FLAG];
    int t = threadIdx.x;
    int blk = blockIdx.x;
    if (blk == 0) {
        // att-MLP pack per o: [0..63]=w1 row, [64..127]=w2 col, [128]=b1
        float* wp = ws + OFF_WPK + (size_t)t * 144;
        for (int d = 0; d < 64; d++) wp[d]      = ldin(w_att1, t * 64 + d, f32);
        for (int d = 0; d < 64; d++) wp[64 + d] = ldin(w_att2, d * 256 + t, f32);
        wp[128] = ldin(b_att1, t, f32);
    } else if (blk == 1) {
        if (t < 64) {
            float* wp = ws + OFF_WPOS + (size_t)t * 80;
            wp[0] = ldin(w_pos1, t * 3 + 0, f32);
            wp[1] = ldin(w_pos1, t * 3 + 1, f32);
            wp[2] = ldin(w_pos1, t * 3 + 2, f32);
            wp[3] = ldin(b_pos1, t, f32);
            for (int d = 0; d < 64; d++) wp[4 + d] = ldin(w_pos2, d * 64 + t, f32);
            ws[OFF_B2 + t]  = ldin(b_att2, t, f32);
            ws[OFF_BP2 + t] = ldin(b_pos2, t, f32);
        }
        for (int i = t; i < 192 * 64; i += 256) ws[OFF_WQKV + i] = ldin(w_qkv, i, f32);
    } else {
        int gid = (blk - 2) * 256 + t;   // 0..16383
        int b = gid >> 12, n = gid & 4095;
        float x = ldin(xyz, (size_t)(b * 3 + 0) * NPTS + n, f32);
        float y = ldin(xyz, (size_t)(b * 3 + 1) * NPTS + n, f32);
        float z = ldin(xyz, (size_t)(b * 3 + 2) * NPTS + n, f32);
        // sq exactly like np.sum(pts*pts,-1): ((x*x + y*y) + z*z), no fma contraction
        float sq = __fadd_rn(__fadd_rn(__fmul_rn(x, x), __fmul_rn(y, y)), __fmul_rn(z, z));
        ((float4*)(ws + OFF_XYZS))[gid] = make_float4(x, y, z, sq);
    }
}

// ---------------- kv GEMM (fast path only): kt/vt row-major [n][d], fp32 ----------------
__global__ void kv_kernel(const void* points, float* ws) {
    __shared__ float T[128 * 65];
    int f32 = (int)((const unsigned*)ws)[OFF_FLAG];
    const float* wq = ws + OFF_WQKV + 64 * 64;  // rows 64..191 (k then v)
    int t = threadIdx.x;
    int wid = __builtin_amdgcn_readfirstlane(t >> 6);
    int lane = t & 63;
    int b = blockIdx.x >> 6;
    int n0 = (blockIdx.x & 63) * 64;

    float P[64];
#pragma unroll
    for (int d = 0; d < 64; d++)
        P[d] = ldin(points, (size_t)(b * 64 + d) * NPTS + n0 + lane, f32);

    for (int i = 0; i < 32; i++) {
        int o = wid + 4 * i;         // wave-uniform, 0..127
        const float* wr = wq + o * 64;
        float acc = 0.f;
#pragma unroll
        for (int d = 0; d < 64; d++) acc = fmaf(wr[d], P[d], acc);
        T[o * 65 + lane] = acc;
    }
    __syncthreads();

#pragma unroll
    for (int a2 = 0; a2 < 2; a2++) {
        float* dst = ws + (a2 == 0 ? OFF_KT : OFF_VT);
#pragma unroll
        for (int j = 0; j < 4; j++) {
            int ci = j * 256 + t;        // 0..1023
            int np = ci >> 4, dp = ci & 15;
            float4 v;
            v.x = T[(a2 * 64 + dp * 4 + 0) * 65 + np];
            v.y = T[(a2 * 64 + dp * 4 + 1) * 65 + np];
            v.z = T[(a2 * 64 + dp * 4 + 2) * 65 + np];
            v.w = T[(a2 * 64 + dp * 4 + 3) * 65 + np];
            *(float4*)(dst + ((size_t)((b << 12) + n0 + np)) * 64 + dp * 4) = v;
        }
    }
}

// ---------------- KNN: wave-per-row, exact top-16 ----------------
template <int NK>
DEVI unsigned long long knn_row(const float4* base, float4 pn, int lane,
                                unsigned* out_row, unsigned long long* kept_worst) {
    unsigned long long arr[NK];
#pragma unroll
    for (int i = 0; i < NK; i++) arr[i] = ~0ull;
    float sqn = pn.w;
#pragma unroll 4
    for (int j = 0; j < 64; j++) {
        int m = (j << 6) + lane;
        float4 pm = base[m];
        float dot = __fadd_rn(__fadd_rn(__fmul_rn(pn.x, pm.x), __fmul_rn(pn.y, pm.y)),
                              __fmul_rn(pn.z, pm.z));
        float d2 = __fsub_rn(__fadd_rn(sqn, pm.w), __fmul_rn(2.0f, dot));
        unsigned ub = __float_as_uint(d2);
        ub = (ub >> 31) ? ~ub : (ub | 0x80000000u);
        unsigned long long key = ((unsigned long long)ub << 32) | (unsigned)m;
#pragma unroll
        for (int i = 0; i < NK; i++) {
            bool lt = key < arr[i];
            unsigned long long lo = lt ? key : arr[i];
            key = lt ? arr[i] : key;
            arr[i] = lo;
        }
    }
    unsigned long long kw = arr[NK - 1];
    unsigned long long v16 = 0;
    for (int r = 0; r < 16; r++) {
        unsigned long long mn = arr[0];
#pragma unroll
        for (int s = 1; s < 64; s <<= 1) {
            unsigned long long o = shflx64(mn, s);
            if (o < mn) mn = o;
        }
        if (arr[0] == mn) {   // exactly one winner (keys unique via embedded m)
#pragma unroll
            for (int i = 0; i < NK - 1; i++) arr[i] = arr[i + 1];
            arr[NK - 1] = ~0ull;
            out_row[r] = (unsigned)(mn & 0xffffffffu);
        }
        v16 = mn;
    }
    *kept_worst = kw;
    return v16;
}

__global__ void knn_kernel(float* ws) {
    int t = threadIdx.x;
    int wid = t >> 6, lane = t & 63;
    int row = blockIdx.x * 4 + wid;      // 0..16383
    int b = row >> 12;
    const float4* base = (const float4*)(ws + OFF_XYZS) + ((size_t)b << 12);
    float4 pn = base[row & 4095];
    unsigned* orow = (unsigned*)(ws + OFF_IDX) + (size_t)row * 16;

    unsigned long long kw;
    unsigned long long v16 = knn_row<6>(base, pn, lane, orow, &kw);
    // if any lane's 6th-best < global 16th, it may have dropped a true member
    if (__any(kw < v16)) {
        knn_row<16>(base, pn, lane, orow, &kw);
    }
}

// ---------------- fused main: q-on-the-fly + pos-MLP + att-MLP + softmax + agg ----------------
// lane = (k 0..15) + 16*(nsub 0..3); wave handles 4 n's; block handles 16 n's.
template <bool USE_KV>
__global__ __launch_bounds__(256) void pt_main(const float* __restrict__ ws,
                                               const void* __restrict__ points,
                                               void* __restrict__ out) {
    __shared__ float PL[64 * 16];   // points block-cols, [d][nl]
    __shared__ float QL[16 * 68];   // q rows, [nl][d] stride 68
    __shared__ float OUTS[64 * 16];

    int f32 = (int)((const unsigned*)ws)[OFF_FLAG];
    const float* wpack = ws + OFF_WPK;
    const float* wpos  = ws + OFF_WPOS;
    const float* b2p   = ws + OFF_B2;
    const float* bp2p  = ws + OFF_BP2;
    const float* wq    = ws + OFF_WQKV;
    const unsigned* idxws = (const unsigned*)(ws + OFF_IDX);
    const float4* xyzs = (const float4*)(ws + OFF_XYZS);

    int t = threadIdx.x;
    int wid = t >> 6, lane = t & 63;
    int b = blockIdx.x >> 8;
    int n0 = (blockIdx.x & 255) * 16;

    // ---- phase 0a: stage this block's 16 point-columns into LDS (fp32)
    {
        int d = t >> 2, c4 = t & 3;
        size_t base = (size_t)(b * 64 + d) * NPTS + n0 + c4 * 4;
        if (f32) {
            float4 pv = *(const float4*)((const float*)points + base);
            PL[d * 16 + c4 * 4 + 0] = pv.x;
            PL[d * 16 + c4 * 4 + 1] = pv.y;
            PL[d * 16 + c4 * 4 + 2] = pv.z;
            PL[d * 16 + c4 * 4 + 3] = pv.w;
        } else {
            ushort4 pv = *(const ushort4*)((const unsigned short*)points + base);
            PL[d * 16 + c4 * 4 + 0] = us2f(pv.x);
            PL[d * 16 + c4 * 4 + 1] = us2f(pv.y);
            PL[d * 16 + c4 * 4 + 2] = us2f(pv.z);
            PL[d * 16 + c4 * 4 + 3] = us2f(pv.w);
        }
    }
    __syncthreads();

    // ---- phase 0b: q[nl][o] for the 16 n's (wave-uniform o, split-d partial dots)
    {
        int sg = lane >> 4, nl = lane & 15;
        for (int oi = 0; oi < 16; oi++) {
            int o = wid * 16 + oi;
            const float* wr = wq + o * 64 + sg * 16;
            float p = 0.f;
#pragma unroll
            for (int j = 0; j < 16; j++) p = fmaf(wr[j], PL[(sg * 16 + j) * 16 + nl], p);
            p += __shfl_xor(p, 16, 64);
            p += __shfl_xor(p, 32, 64);
            if (lane < 16) QL[nl * 68 + o] = p;
        }
    }
    __syncthreads();

    // ---- per-lane task: (n, k)
    int k = lane & 15, nsub = lane >> 4;
    int nl = wid * 4 + nsub;
    int n = n0 + nl;
    int row = (b << 12) + n;
    unsigned m = idxws[(size_t)row * 16 + k] & 4095u;
    int mrow = (b << 12) + (int)m;

    float4 pn = xyzs[row];
    float4 pmx = xyzs[mrow];
    float rx = pn.x - pmx.x, ry = pn.y - pmx.y, rz = pn.z - pmx.z;

    // ---- pos MLP
    float rpe[64];
#pragma unroll
    for (int d = 0; d < 64; d++) rpe[d] = bp2p[d];
#pragma unroll 2
    for (int o = 0; o < 64; o++) {
        const float* wr = wpos + o * 80;
        float hp = fmaf(wr[0], rx, fmaf(wr[1], ry, fmaf(wr[2], rz, wr[3])));
        hp = fmaxf(hp, 0.f);
#pragma unroll
        for (int d = 0; d < 64; d++) rpe[d] = fmaf(wr[4 + d], hp, rpe[d]);
    }

    // ---- X[d] = (q[n][d] - k[m][d]) + rpe[d]
    float Pm[USE_KV ? 1 : 64];
    if constexpr (!USE_KV) {
#pragma unroll
        for (int d = 0; d < 64; d++)
            Pm[d] = ldin(points, ((size_t)(b * 64 + d) << 12) + (int)m, f32);
    }

    float X[64];
    if constexpr (USE_KV) {
        const float4* q4 = (const float4*)(QL + nl * 68);
        const float4* kr = (const float4*)(ws + OFF_KT + (size_t)mrow * 64);
#pragma unroll
        for (int d4 = 0; d4 < 16; d4++) {
            float4 qv = q4[d4];
            float4 kv = kr[d4];
            X[4 * d4 + 0] = (qv.x - kv.x) + rpe[4 * d4 + 0];
            X[4 * d4 + 1] = (qv.y - kv.y) + rpe[4 * d4 + 1];
            X[4 * d4 + 2] = (qv.z - kv.z) + rpe[4 * d4 + 2];
            X[4 * d4 + 3] = (qv.w - kv.w) + rpe[4 * d4 + 3];
        }
    } else {
        const float* qrow = QL + nl * 68;
#pragma unroll 2
        for (int d = 0; d < 64; d++) {
            const float* wr = wq + (64 + d) * 64;
            float kd = 0.f;
#pragma unroll
            for (int dd = 0; dd < 64; dd++) kd = fmaf(wr[dd], Pm[dd], kd);
            X[d] = (qrow[d] - kd) + rpe[d];
        }
    }

    // ---- att MLP
    float sim[64];
#pragma unroll
    for (int d = 0; d < 64; d++) sim[d] = b2p[d];
#pragma unroll 2
    for (int o = 0; o < 256; o++) {
        const float* wr = wpack + (size_t)o * 144;
        float h = wr[128];
#pragma unroll
        for (int d = 0; d < 64; d++) h = fmaf(wr[d], X[d], h);
        h = fmaxf(h, 0.f);
#pragma unroll
        for (int d = 0; d < 64; d++) sim[d] = fmaf(wr[64 + d], h, sim[d]);
    }

    // ---- softmax over k (16-lane groups) + agg
    {
        const float4* vr = USE_KV ? (const float4*)(ws + OFF_VT + (size_t)mrow * 64) : nullptr;
#pragma unroll
        for (int d4 = 0; d4 < 16; d4++) {
            float vvv[4];
            if constexpr (USE_KV) {
                float4 vv = vr[d4];
                vvv[0] = vv.x; vvv[1] = vv.y; vvv[2] = vv.z; vvv[3] = vv.w;
            } else {
#pragma unroll
                for (int j = 0; j < 4; j++) {
                    const float* wr = wq + (128 + 4 * d4 + j) * 64;
                    float vd = 0.f;
#pragma unroll
                    for (int dd = 0; dd < 64; dd++) vd = fmaf(wr[dd], Pm[dd], vd);
                    vvv[j] = vd;
                }
            }
#pragma unroll
            for (int j = 0; j < 4; j++) {
                int d = 4 * d4 + j;
                float s = sim[d];
                float mx = s;
                mx = fmaxf(mx, __shfl_xor(mx, 1, 64));
                mx = fmaxf(mx, __shfl_xor(mx, 2, 64));
                mx = fmaxf(mx, __shfl_xor(mx, 4, 64));
                mx = fmaxf(mx, __shfl_xor(mx, 8, 64));
                float e = __expf(s - mx);
                float sm = e;
                sm += __shfl_xor(sm, 1, 64);
                sm += __shfl_xor(sm, 2, 64);
                sm += __shfl_xor(sm, 4, 64);
                sm += __shfl_xor(sm, 8, 64);
                float v2 = vvv[j] + rpe[d];
                float p = e * v2;
                p += __shfl_xor(p, 1, 64);
                p += __shfl_xor(p, 2, 64);
                p += __shfl_xor(p, 4, 64);
                p += __shfl_xor(p, 8, 64);
                if (k == 0) OUTS[d * 16 + nl] = p / sm;
            }
        }
    }
    __syncthreads();

    // coalesced store (dtype-dispatched)
    {
        int d = t >> 2, c = t & 3;
        float4 v = *(const float4*)&OUTS[d * 16 + c * 4];
        size_t ofs = (size_t)(b * 64 + d) * NPTS + n0 + c * 4;
        if (f32) {
            *(float4*)((float*)out + ofs) = v;
        } else {
            uint2 pk;
            pk.x = (unsigned)f2us(v.x) | ((unsigned)f2us(v.y) << 16);
            pk.y = (unsigned)f2us(v.z) | ((unsigned)f2us(v.w) << 16);
            *(uint2*)((unsigned short*)out + ofs) = pk;
        }
    }
}

// ---------------- host ----------------
extern "C" void kernel_launch(void* const* d_in, const int* in_sizes, int n_in,
                              void* d_out, int out_size, void* d_ws, size_t ws_size,
                              hipStream_t stream) {
    const void* xyz    = d_in[0];
    const void* points = d_in[1];
    const void* w_qkv  = d_in[2];
    const void* w_pos1 = d_in[3];
    const void* b_pos1 = d_in[4];
    const void* w_pos2 = d_in[5];
    const void* b_pos2 = d_in[6];
    const void* w_att1 = d_in[7];
    const void* b_att1 = d_in[8];
    const void* w_att2 = d_in[9];
    const void* b_att2 = d_in[10];
    float* ws = (float*)d_ws;

    // ws_size is constant across calls -> same path every call (graph-safe)
    bool use_kv = ws_size >= FULL_FLOATS * sizeof(float);

    hipLaunchKernelGGL(detect_kernel, dim3(1), dim3(256), 0, stream,
                       xyz, (unsigned*)ws + OFF_FLAG);
    hipLaunchKernelGGL(prep_kernel, dim3(66), dim3(256), 0, stream,
                       xyz, w_qkv, w_pos1, b_pos1, w_pos2, b_pos2,
                       w_att1, b_att1, w_att2, b_att2, ws);
    if (use_kv)
        hipLaunchKernelGGL(kv_kernel, dim3(256), dim3(256), 0, stream, points, ws);
    hipLaunchKernelGGL(knn_kernel, dim3(4096), dim3(256), 0, stream, ws);
    if (use_kv)
        hipLaunchKernelGGL((pt_main<true>),  dim3(1024), dim3(256), 0, stream, (const float*)ws, points, d_out);
    else
        hipLaunchKernelGGL((pt_main<false>), dim3(1024), dim3(256), 0, stream, (const float*)ws, points, d_out);
}